// Round 8
// baseline (21.405 us; speedup 1.0000x reference)
//
#include <hip/hip_runtime.h>
#include <hip/hip_bf16.h>

typedef _Float16 f16x8 __attribute__((ext_vector_type(8)));
typedef _Float16 hf2   __attribute__((ext_vector_type(2)));
typedef __fp16  fp16x2 __attribute__((ext_vector_type(2)));
typedef float f32x4 __attribute__((ext_vector_type(4)));

#define IN_F 128
#define OUT_F 16
#define NB 16
// K = 2048 = 64 K-steps of 32. K-step ks = 8P + 2q + h (P=0..7, q=0..3, h=0..1).
// OPERAND SWAP: A = w (rows = 16 outputs), B = basis (cols = 16 batch rows).
// Wave wv owns P = wv (8 K-steps) -> its w A-frags = 8 x f16x8 = 32 VGPRs, loaded
// once. k-slot (g = lane>>4, j): f = 16P + 4g + q, n = 8h + j — same pairing on A
// and B sides (convention proven by the previous passing kernel, roles exchanged).
// Per 16-row tile: 1 x-float4/lane, 4 cheb chains, 8 MFMA, zero LDS reads.
// 8 waves' K-partials reduced per tile via LDS (double-buffered, rotating reducer,
// fixed-order f32 adds -> deterministic).
//
// LDS w staging (32 KB/round, round r = P in [4r,4r+4)): 16B slot
//   s = 128*o + 32*(P&3) + 8*g + ((2q+h) ^ (o&7))     [XOR keeps reads conflict-free]
// holding w[o][16P+4g+q][8h..8h+7] as f16.

__device__ __forceinline__ void cheb_frags(float xv, f16x8& ae, f16x8& ao) {
    // pairs h[j] = (T_2j, T_2j+1): h[j+1] = u*h[j] - h[j-1], u = 2*T2 = 4x^2-2
    float T2 = __builtin_fmaf(xv + xv, xv, -1.0f);
    float T3 = __builtin_fmaf(xv + xv, T2, -xv);
    float u  = T2 + T2;
    hf2 h0 = __builtin_bit_cast(hf2, __builtin_amdgcn_cvt_pkrtz(1.0f, xv));
    hf2 h1 = __builtin_bit_cast(hf2, __builtin_amdgcn_cvt_pkrtz(T2, T3));
    hf2 uu = __builtin_bit_cast(hf2, __builtin_amdgcn_cvt_pkrtz(u, u));
    hf2 h2 = __builtin_elementwise_fma(uu, h1, -h0);
    hf2 h3 = __builtin_elementwise_fma(uu, h2, -h1);
    hf2 h4 = __builtin_elementwise_fma(uu, h3, -h2);
    hf2 h5 = __builtin_elementwise_fma(uu, h4, -h3);
    hf2 h6 = __builtin_elementwise_fma(uu, h5, -h4);
    hf2 h7 = __builtin_elementwise_fma(uu, h6, -h5);
    union { f16x8 v; hf2 h[4]; } e, od;
    e.h[0] = h0;  e.h[1] = h1;  e.h[2] = h2;  e.h[3] = h3;
    od.h[0] = h4; od.h[1] = h5; od.h[2] = h6; od.h[3] = h7;
    ae = e.v;
    ao = od.v;
}

// block = 512 threads = 8 waves (wave wv = K-slice P=wv); 8 tiles x 16 rows = 128
// rows/block; grid = 512 -> 2 blocks/CU (96KB LDS/CU), 16 waves/CU = 4/SIMD.
__global__ __launch_bounds__(512, 4) void cheb_fused(const float* __restrict__ x,
                                                     const float* __restrict__ w,
                                                     float* __restrict__ out) {
    __shared__ f16x8 wlds[2048];               // 32 KB staging (half of w per round)
    __shared__ f32x4 red[2][8][64];            // 16 KB reduce, double-buffered

    const int tid = threadIdx.x;
    const int l  = tid & 63;
    const int wv = tid >> 6;                   // 0..7  == global P
    const int g  = l >> 4;
    const int m  = l & 15;                     // tile row (B col) / output o (A row)
    const long row0 = (long)blockIdx.x * 128;

    // preload all x for this block: 8 tiles, one float4 per lane per tile
    // lane covers x[row0+16t+m][16wv+4g .. +3]; wave = 16 rows x 64B lines.
    const f32x4* x4 = (const f32x4*)x;
    f32x4 xt[8];
    #pragma unroll
    for (int t = 0; t < 8; ++t)
        xt[t] = x4[(row0 + t * 16 + m) * 32 + wv * 4 + g];

    // two-round w conversion (all 512 threads) + per-wave frag pickup
    f16x8 wreg[8];
    const int key = m & 7;
    #pragma unroll
    for (int r = 0; r < 2; ++r) {
        #pragma unroll
        for (int pp = 0; pp < 2; ++pp) {
            int p = 2 * tid + pp;              // pair = (o, fl), fl local feature
            int o = p >> 6, fl = p & 63;
            int Pp = fl >> 4, gg = (fl >> 2) & 3, q = fl & 3, ky = o & 7;
            const float4* src = (const float4*)(w + ((size_t)(o * 128 + 64 * r + fl)) * 16);
            float4 a = src[0], b = src[1], c = src[2], d = src[3];
            union { f16x8 v; fp16x2 h[4]; } E, O;
            E.h[0] = __builtin_amdgcn_cvt_pkrtz(a.x, a.y);
            E.h[1] = __builtin_amdgcn_cvt_pkrtz(a.z, a.w);
            E.h[2] = __builtin_amdgcn_cvt_pkrtz(b.x, b.y);
            E.h[3] = __builtin_amdgcn_cvt_pkrtz(b.z, b.w);
            O.h[0] = __builtin_amdgcn_cvt_pkrtz(c.x, c.y);
            O.h[1] = __builtin_amdgcn_cvt_pkrtz(c.z, c.w);
            O.h[2] = __builtin_amdgcn_cvt_pkrtz(d.x, d.y);
            O.h[3] = __builtin_amdgcn_cvt_pkrtz(d.z, d.w);
            int sb = 128 * o + 32 * Pp + 8 * gg;
            wlds[sb + ((2 * q) ^ ky)]     = E.v;
            wlds[sb + ((2 * q + 1) ^ ky)] = O.v;
        }
        __syncthreads();
        if ((wv >> 2) == r) {                  // waves whose P is in this round
            int Pl = wv & 3;
            #pragma unroll
            for (int q = 0; q < 4; ++q)
                #pragma unroll
                for (int h = 0; h < 2; ++h)
                    wreg[2 * q + h] = wlds[128 * m + 32 * Pl + 8 * g + ((2 * q + h) ^ key)];
        }
        __syncthreads();
    }

    // main loop: 8 tiles; zero LDS reads in compute; 1 barrier + LDS reduce per tile
    #pragma unroll
    for (int t = 0; t < 8; ++t) {
        f32x4 acc = {0.f, 0.f, 0.f, 0.f};
        #pragma unroll
        for (int q = 0; q < 4; ++q) {
            f16x8 ae, ao;
            cheb_frags(xt[t][q], ae, ao);
            acc = __builtin_amdgcn_mfma_f32_16x16x32_f16(wreg[2 * q],     ae, acc, 0, 0, 0);
            acc = __builtin_amdgcn_mfma_f32_16x16x32_f16(wreg[2 * q + 1], ao, acc, 0, 0, 0);
        }
        red[t & 1][wv][l] = acc;
        __syncthreads();
        if (wv == t) {                         // rotating reducer wave
            f32x4 s = red[t & 1][0][l];
            #pragma unroll
            for (int k = 1; k < 8; ++k) s += red[t & 1][k][l];
            // D layout: row = 4g+rr = output, col = m = batch row within tile
            *(f32x4*)&out[(row0 + t * 16 + m) * OUT_F + 4 * g] = s;
        }
    }
}

extern "C" void kernel_launch(void* const* d_in, const int* in_sizes, int n_in,
                              void* d_out, int out_size, void* d_ws, size_t ws_size,
                              hipStream_t stream) {
    const float* x = (const float*)d_in[0];
    const float* w = (const float*)d_in[1];
    float* out = (float*)d_out;
    cheb_fused<<<512, 512, 0, stream>>>(x, w, out);
}

// Round 9
// 16.248 us; speedup vs baseline: 1.3174x; 1.3174x over previous
//
#include <hip/hip_runtime.h>
#include <hip/hip_bf16.h>

typedef _Float16 f16x8 __attribute__((ext_vector_type(8)));
typedef _Float16 hf2   __attribute__((ext_vector_type(2)));
typedef __fp16  fp16x2 __attribute__((ext_vector_type(2)));
typedef float f32x4 __attribute__((ext_vector_type(4)));

#define IN_F 128
#define OUT_F 16
#define NB 16
// K = 2048 = 64 K-steps of 32. K-step ks = 8P + 2q + h (P=0..7, q=0..3, h=0..1).
// Orientation (same as R7): A = cheb basis (rows = batch), B = w (cols = outputs).
// A-slot j of lane l at ks holds T_{8h+j}(x[row][f]), f = 16P + 4g + q (g = l>>4).
// Wave = (rg, kh): rows rg*32..+31 (2 MFMA tiles sharing B-frags), K-steps of
// P in [4kh, 4kh+4). 4096 waves total = 4 waves/SIMD, and LDS B-frag traffic is
// HALVED vs R7 (32 reads serve 64 MFMA per wave). K-halves combined by ONE
// LDS reduction + single barrier per block (fixed-order f32 adds, deterministic).
// LDS w layout (R7): 16B slot for (o,f,h) = (2*(o*128+f) + h) ^ (o&7).

__device__ __forceinline__ void cheb_frags(float xv, f16x8& ae, f16x8& ao) {
    // pairs h[j] = (T_2j, T_2j+1): h[j+1] = u*h[j] - h[j-1], u = 2*T2 = 4x^2-2
    float T2 = __builtin_fmaf(xv + xv, xv, -1.0f);
    float T3 = __builtin_fmaf(xv + xv, T2, -xv);
    float u  = T2 + T2;
    hf2 h0 = __builtin_bit_cast(hf2, __builtin_amdgcn_cvt_pkrtz(1.0f, xv));
    hf2 h1 = __builtin_bit_cast(hf2, __builtin_amdgcn_cvt_pkrtz(T2, T3));
    hf2 uu = __builtin_bit_cast(hf2, __builtin_amdgcn_cvt_pkrtz(u, u));
    hf2 h2 = __builtin_elementwise_fma(uu, h1, -h0);
    hf2 h3 = __builtin_elementwise_fma(uu, h2, -h1);
    hf2 h4 = __builtin_elementwise_fma(uu, h3, -h2);
    hf2 h5 = __builtin_elementwise_fma(uu, h4, -h3);
    hf2 h6 = __builtin_elementwise_fma(uu, h5, -h4);
    hf2 h7 = __builtin_elementwise_fma(uu, h6, -h5);
    union { f16x8 v; hf2 h[4]; } e, od;
    e.h[0] = h0;  e.h[1] = h1;  e.h[2] = h2;  e.h[3] = h3;
    od.h[0] = h4; od.h[1] = h5; od.h[2] = h6; od.h[3] = h7;
    ae = e.v;
    ao = od.v;
}

// block = 512 threads = 8 waves = 4 row-groups x 2 K-halves; 128 rows/block;
// grid = 512 -> 2 blocks/CU (144KB LDS/CU), 16 waves/CU = 4 waves/SIMD.
__global__ __launch_bounds__(512, 4) void cheb_fused(const float* __restrict__ x,
                                                     const float* __restrict__ w,
                                                     float* __restrict__ out) {
    __shared__ _Float16 wlds[32768];           // 64 KB w fragments
    __shared__ f32x4 red[4][2][64];            // 8 KB K-half reduction

    const int tid = threadIdx.x;
    const int l  = tid & 63;
    const int wv = tid >> 6;                   // 0..7
    const int rg = wv >> 1;                    // row-group 0..3
    const int kh = wv & 1;                     // K-half
    const int g  = l >> 4;
    const int m  = l & 15;                     // A row within tile == B col (output o)
    const long row0 = (long)blockIdx.x * 128;

    const long r0 = row0 + rg * 32 + m;        // tile0 row; tile1 = r0 + 16
    const f32x4* x4 = (const f32x4*)x;

    // x preload for this wave's K-half: cols 16(4kh+Pl)+4g..+3, Pl = 0..3
    f32x4 xa[4], xb[4];
    #pragma unroll
    for (int Pl = 0; Pl < 4; ++Pl) {
        xa[Pl] = x4[r0 * 32 + (4 * kh + Pl) * 4 + g];
        xb[Pl] = x4[(r0 + 16) * 32 + (4 * kh + Pl) * 4 + g];
    }

    // convert w -> LDS fragment layout: 2048 (o,f) pairs over 512 threads;
    // 64B coalesced global read per pair, two swizzled 16B LDS writes.
    #pragma unroll
    for (int k = 0; k < 4; ++k) {
        int p = k * 512 + tid;                 // p = o*128 + f
        const float4* src = (const float4*)(w + (size_t)p * 16);
        float4 a = src[0], b = src[1], c = src[2], d = src[3];
        union { f16x8 v; fp16x2 h[4]; } E, O;
        E.h[0] = __builtin_amdgcn_cvt_pkrtz(a.x, a.y);
        E.h[1] = __builtin_amdgcn_cvt_pkrtz(a.z, a.w);
        E.h[2] = __builtin_amdgcn_cvt_pkrtz(b.x, b.y);
        E.h[3] = __builtin_amdgcn_cvt_pkrtz(b.z, b.w);
        O.h[0] = __builtin_amdgcn_cvt_pkrtz(c.x, c.y);
        O.h[1] = __builtin_amdgcn_cvt_pkrtz(c.z, c.w);
        O.h[2] = __builtin_amdgcn_cvt_pkrtz(d.x, d.y);
        O.h[3] = __builtin_amdgcn_cvt_pkrtz(d.z, d.w);
        int s0 = (2 * p) ^ ((p >> 7) & 7);     // ^ (o&7)
        *(f16x8*)&wlds[s0 * 8]       = E.v;
        *(f16x8*)&wlds[(s0 ^ 1) * 8] = O.v;
    }
    __syncthreads();

    f32x4 acc0 = {0.f, 0.f, 0.f, 0.f};
    f32x4 acc1 = {0.f, 0.f, 0.f, 0.f};

    const int Aslot = 256 * m + 8 * g;         // slot = Aslot + 32P + (2q ^ key)
    const int key = m & 7;

    #pragma unroll
    for (int Pl = 0; Pl < 4; ++Pl) {
        int P = 4 * kh + Pl;
        #pragma unroll
        for (int q = 0; q < 4; ++q) {
            int s0 = Aslot + 32 * P + ((2 * q) ^ key);
            f16x8 b0 = *(const f16x8*)&wlds[s0 * 8];
            f16x8 b1 = *(const f16x8*)&wlds[(s0 ^ 1) * 8];
            f16x8 a0e, a0o, a1e, a1o;
            cheb_frags(xa[Pl][q], a0e, a0o);
            cheb_frags(xb[Pl][q], a1e, a1o);
            acc0 = __builtin_amdgcn_mfma_f32_16x16x32_f16(a0e, b0, acc0, 0, 0, 0);
            acc0 = __builtin_amdgcn_mfma_f32_16x16x32_f16(a0o, b1, acc0, 0, 0, 0);
            acc1 = __builtin_amdgcn_mfma_f32_16x16x32_f16(a1e, b0, acc1, 0, 0, 0);
            acc1 = __builtin_amdgcn_mfma_f32_16x16x32_f16(a1o, b1, acc1, 0, 0, 0);
        }
    }

    // combine K-halves: kh=1 publishes, kh=0 adds (fixed order) and stores.
    if (kh) {
        red[rg][0][l] = acc0;
        red[rg][1][l] = acc1;
    }
    __syncthreads();
    if (!kh) {
        acc0 += red[rg][0][l];
        acc1 += red[rg][1][l];
        // D layout: col = m (output o), row = 4g + rr (batch row within tile)
        float* op = out + (row0 + rg * 32 + 4 * g) * OUT_F + m;
        #pragma unroll
        for (int rr = 0; rr < 4; ++rr) {
            op[rr * OUT_F] = acc0[rr];
            op[(16 + rr) * OUT_F] = acc1[rr];
        }
    }
}

extern "C" void kernel_launch(void* const* d_in, const int* in_sizes, int n_in,
                              void* d_out, int out_size, void* d_ws, size_t ws_size,
                              hipStream_t stream) {
    const float* x = (const float*)d_in[0];
    const float* w = (const float*)d_in[1];
    float* out = (float*)d_out;
    cheb_fused<<<512, 512, 0, stream>>>(x, w, out);
}